// Round 2
// baseline (991.474 us; speedup 1.0000x reference)
//
#include <hip/hip_runtime.h>

#define NN 256
#define CC 512
#define OO 1024
#define BB 64

#define F_QR 0.1f
#define F_KR 0.1f
#define F_SVE 0.1f

__device__ inline float4 bn4(float4 v, float sc, float hh) {
  return make_float4(v.x * sc + hh, v.y * sc + hh, v.z * sc + hh, v.w * sc + hh);
}
__device__ inline float4 mul4(float4 v, float s) {
  return make_float4(v.x * s, v.y * s, v.z * s, v.w * s);
}

// ---------------- K1: qkv[b][o][n] = sum_c W[o][c] * x[b][n][c] ----------------
__global__ __launch_bounds__(256) void k_qkv_gemm(const float* __restrict__ x,
                                                  const float* __restrict__ w,
                                                  float* __restrict__ qkv) {
  const int b = blockIdx.z, ot = blockIdx.y, nt = blockIdx.x;
  const int o0 = ot * 128, n0 = nt * 128;
  __shared__ float As[32][132];  // [c][o]
  __shared__ float Bs[32][132];  // [c][n]
  const int t = threadIdx.x;
  const int to = t >> 4, tn = t & 15;
  float acc[8][8];
#pragma unroll
  for (int i = 0; i < 8; ++i)
#pragma unroll
    for (int j = 0; j < 8; ++j) acc[i][j] = 0.f;

  const float* wbase = w + (size_t)o0 * CC;
  const float* xbase = x + (size_t)b * NN * CC + (size_t)n0 * CC;

  for (int c0 = 0; c0 < CC; c0 += 32) {
#pragma unroll
    for (int r = 0; r < 4; ++r) {
      int f = t + 256 * r;
      int row = f >> 3, cq = f & 7;
      float4 w4 = *(const float4*)(wbase + (size_t)row * CC + c0 + cq * 4);
      As[cq * 4 + 0][row] = w4.x; As[cq * 4 + 1][row] = w4.y;
      As[cq * 4 + 2][row] = w4.z; As[cq * 4 + 3][row] = w4.w;
      float4 x4 = *(const float4*)(xbase + (size_t)row * CC + c0 + cq * 4);
      Bs[cq * 4 + 0][row] = x4.x; Bs[cq * 4 + 1][row] = x4.y;
      Bs[cq * 4 + 2][row] = x4.z; Bs[cq * 4 + 3][row] = x4.w;
    }
    __syncthreads();
#pragma unroll
    for (int kk = 0; kk < 32; ++kk) {
      float a[8], bb[8];
      *(float4*)&a[0] = *(const float4*)&As[kk][to * 8];
      *(float4*)&a[4] = *(const float4*)&As[kk][to * 8 + 4];
      *(float4*)&bb[0] = *(const float4*)&Bs[kk][tn * 8];
      *(float4*)&bb[4] = *(const float4*)&Bs[kk][tn * 8 + 4];
#pragma unroll
      for (int i = 0; i < 8; ++i)
#pragma unroll
        for (int j = 0; j < 8; ++j) acc[i][j] += a[i] * bb[j];
    }
    __syncthreads();
  }
#pragma unroll
  for (int i = 0; i < 8; ++i) {
    float* dst = qkv + ((size_t)b * OO + o0 + to * 8 + i) * NN + n0 + tn * 8;
    float4 v0 = {acc[i][0], acc[i][1], acc[i][2], acc[i][3]};
    float4 v1 = {acc[i][4], acc[i][5], acc[i][6], acc[i][7]};
    *(float4*)dst = v0;
    *(float4*)(dst + 4) = v1;
  }
}

// ---------------- K2: per-channel BN scale/shift for qkv ----------------
__global__ __launch_bounds__(256) void k_qkv_stats(const float* __restrict__ qkv,
                                                   const float* __restrict__ gq,
                                                   const float* __restrict__ bq,
                                                   float* __restrict__ qs,
                                                   float* __restrict__ qh) {
  const int o = blockIdx.x;
  const int t = threadIdx.x;
  float s = 0.f, ss = 0.f;
  for (int b = 0; b < BB; ++b) {
    float v = qkv[((size_t)b * OO + o) * NN + t];
    s += v; ss += v * v;
  }
#pragma unroll
  for (int m = 1; m < 64; m <<= 1) { s += __shfl_xor(s, m); ss += __shfl_xor(ss, m); }
  __shared__ float rs[4], rss[4];
  int wv = t >> 6;
  if ((t & 63) == 0) { rs[wv] = s; rss[wv] = ss; }
  __syncthreads();
  if (t == 0) {
    s = rs[0] + rs[1] + rs[2] + rs[3];
    ss = rss[0] + rss[1] + rss[2] + rss[3];
    const float inv = 1.f / (float)(BB * NN);
    float m = s * inv;
    float var = ss * inv - m * m;
    float r = rsqrtf(var + 1e-5f);
    float sc = gq[o] * r;
    qs[o] = sc;
    qh[o] = bq[o] - m * sc;
  }
}

// ---------------- pass1: stats of qk/qr/kr (with F scalars applied) ----------------
__device__ inline void reduce_term(float (&acc)[4][16], int term, float F, float* s_sh) {
  float s = 0.f, ss = 0.f;
#pragma unroll
  for (int di = 0; di < 4; ++di)
#pragma unroll
    for (int dj = 0; dj < 16; ++dj) { float v = acc[di][dj]; s += v; ss += v * v; }
  s *= F;
  ss *= F * F;
#pragma unroll
  for (int m = 1; m < 64; m <<= 1) { s += __shfl_xor(s, m); ss += __shfl_xor(ss, m); }
  if ((threadIdx.x & 63) == 0) {
    atomicAdd(&s_sh[term * 2 + 0], s);
    atomicAdd(&s_sh[term * 2 + 1], ss);
  }
}

__global__ __launch_bounds__(256) void k_pass1(const float* __restrict__ qkv,
                                               const float* __restrict__ rel,
                                               const float* __restrict__ qs,
                                               const float* __restrict__ qh,
                                               float* __restrict__ simacc) {
  __shared__ float qt[32 * 64];
  __shared__ float kt[32 * 256];
  __shared__ float s_sh[6];
  const int it = blockIdx.x, bg = blockIdx.y;
  const int b = bg >> 3, g = bg & 7, i0 = it * 64;
  const int t = threadIdx.x, rg = t >> 4, cg = t & 15;
  if (t < 6) s_sh[t] = 0.f;

#pragma unroll
  for (int r = 0; r < 2; ++r) {
    int f = t + 256 * r;
    int row = f >> 4, c4 = f & 15;
    int o = g * 128 + row;
    float sc = qs[o], hh = qh[o];
    float4 v = *(const float4*)(qkv + ((size_t)b * OO + o) * NN + i0 + c4 * 4);
    *(float4*)&qt[row * 64 + c4 * 4] = bn4(v, sc, hh);
  }
#pragma unroll
  for (int r = 0; r < 8; ++r) {
    int f = t + 256 * r;
    int row = f >> 6, c4 = f & 63;
    int o = g * 128 + 32 + row;
    float sc = qs[o], hh = qh[o];
    float4 v = *(const float4*)(qkv + ((size_t)b * OO + o) * NN + c4 * 4);
    *(float4*)&kt[row * 256 + c4 * 4] = bn4(v, sc, hh);
  }
  __syncthreads();

  float acc[4][16];
  // ---- qk ----
#pragma unroll
  for (int di = 0; di < 4; ++di)
#pragma unroll
    for (int dj = 0; dj < 16; ++dj) acc[di][dj] = 0.f;
  for (int c = 0; c < 32; ++c) {
    float q4[4];
    *(float4*)q4 = *(const float4*)&qt[c * 64 + rg * 4];
    float k16[16];
#pragma unroll
    for (int q = 0; q < 4; ++q) *(float4*)&k16[q * 4] = *(const float4*)&kt[c * 256 + cg * 16 + q * 4];
#pragma unroll
    for (int di = 0; di < 4; ++di)
#pragma unroll
      for (int dj = 0; dj < 16; ++dj) acc[di][dj] += q4[di] * k16[dj];
  }
  reduce_term(acc, 0, 1.0f, s_sh);

  // ---- qr ----
#pragma unroll
  for (int di = 0; di < 4; ++di)
#pragma unroll
    for (int dj = 0; dj < 16; ++dj) acc[di][dj] = 0.f;
  const int baseq = i0 + rg * 4 - cg * 16 + 240;
  for (int c = 0; c < 32; ++c) {
    float q4[4];
    *(float4*)q4 = *(const float4*)&qt[c * 64 + rg * 4];
    float rq[19];
    const float* rp = rel + (size_t)c * 511 + baseq;
#pragma unroll
    for (int u = 0; u < 19; ++u) rq[u] = rp[u];
#pragma unroll
    for (int di = 0; di < 4; ++di)
#pragma unroll
      for (int dj = 0; dj < 16; ++dj) acc[di][dj] += q4[di] * rq[di - dj + 15];
  }
  reduce_term(acc, 1, F_QR, s_sh);

  // ---- kr ----
#pragma unroll
  for (int di = 0; di < 4; ++di)
#pragma unroll
    for (int dj = 0; dj < 16; ++dj) acc[di][dj] = 0.f;
  const int basek = cg * 16 - rg * 4 - i0 + 252;
  for (int c = 0; c < 32; ++c) {
    float k16[16];
#pragma unroll
    for (int q = 0; q < 4; ++q) *(float4*)&k16[q * 4] = *(const float4*)&kt[c * 256 + cg * 16 + q * 4];
    float rk[19];
    const float* rp = rel + (size_t)(32 + c) * 511 + basek;
#pragma unroll
    for (int u = 0; u < 19; ++u) rk[u] = rp[u];
#pragma unroll
    for (int di = 0; di < 4; ++di)
#pragma unroll
      for (int dj = 0; dj < 16; ++dj) acc[di][dj] += k16[dj] * rk[dj - di + 3];
  }
  reduce_term(acc, 2, F_KR, s_sh);

  __syncthreads();
  if (t < 6) {
    int term = t >> 1, isq = t & 1;
    atomicAdd(&simacc[isq * 24 + term * 8 + g], s_sh[t]);
  }
}

// ---------------- finalize sim BN coefficients ----------------
__global__ void k_sim_finalize(const float* __restrict__ simacc,
                               const float* __restrict__ gs,
                               const float* __restrict__ bs,
                               float* __restrict__ simscale,
                               float* __restrict__ simshift) {
  const int t = threadIdx.x;
  __shared__ float sh[24];
  if (t < 24) {
    const float inv = 1.f / (64.f * 256.f * 256.f);
    float m = simacc[t] * inv;
    float var = simacc[24 + t] * inv - m * m;
    float a = gs[t] * rsqrtf(var + 1e-5f);
    simscale[t] = a;
    sh[t] = bs[t] - m * a;
  }
  __syncthreads();
  if (t < 8) simshift[t] = sh[t] + sh[8 + t] + sh[16 + t];
}

// ---------------- pass2: sim + softmax + sv/sve ----------------
__global__ __launch_bounds__(256) void k_pass2(const float* __restrict__ qkv,
                                               const float* __restrict__ rel,
                                               const float* __restrict__ qs,
                                               const float* __restrict__ qh,
                                               const float* __restrict__ simscale,
                                               const float* __restrict__ simshift,
                                               float* __restrict__ svbuf,
                                               float* __restrict__ svebuf) {
  __shared__ float smem[12288];  // 48 KB
  float* const qta = smem;          // [32][64]
  float* const qtr = smem + 2048;   // [32][64]
  float* const kt  = smem + 4096;   // [32][256]
  float* const ktr = smem;          // [32][256] phase A2 (overlaps qta/qtr/kt half)
  float* const vt  = smem;          // [32][256] phase B

  const int it = blockIdx.x, bg = blockIdx.y;
  const int b = bg >> 3, g = bg & 7, i0 = it * 64;
  const int t = threadIdx.x, rg = t >> 4, cg = t & 15;
  // Fold the reference's F_QR/F_KR scalars into the BN scales so the logits
  // match sum of BN(F*term) exactly (eps makes this non-invariant).
  const float aQK = simscale[g];
  const float aQR = F_QR * simscale[8 + g];
  const float aKR = F_KR * simscale[16 + g];
  const float SH = simshift[g];

#pragma unroll
  for (int r = 0; r < 2; ++r) {
    int f = t + 256 * r;
    int row = f >> 4, c4 = f & 15;
    int o = g * 128 + row;
    float sc = qs[o], hh = qh[o];
    float4 v = *(const float4*)(qkv + ((size_t)b * OO + o) * NN + i0 + c4 * 4);
    float4 uq = bn4(v, sc, hh);
    *(float4*)&qta[row * 64 + c4 * 4] = mul4(uq, aQK);
    *(float4*)&qtr[row * 64 + c4 * 4] = mul4(uq, aQR);
  }
#pragma unroll
  for (int r = 0; r < 8; ++r) {
    int f = t + 256 * r;
    int row = f >> 6, c4 = f & 63;
    int o = g * 128 + 32 + row;
    float sc = qs[o], hh = qh[o];
    float4 v = *(const float4*)(qkv + ((size_t)b * OO + o) * NN + c4 * 4);
    *(float4*)&kt[row * 256 + c4 * 4] = bn4(v, sc, hh);
  }
  __syncthreads();

  float p[4][16];
#pragma unroll
  for (int di = 0; di < 4; ++di)
#pragma unroll
    for (int dj = 0; dj < 16; ++dj) p[di][dj] = 0.f;

  // qk (aQK folded into qta)
  for (int c = 0; c < 32; ++c) {
    float q4[4];
    *(float4*)q4 = *(const float4*)&qta[c * 64 + rg * 4];
    float k16[16];
#pragma unroll
    for (int q = 0; q < 4; ++q) *(float4*)&k16[q * 4] = *(const float4*)&kt[c * 256 + cg * 16 + q * 4];
#pragma unroll
    for (int di = 0; di < 4; ++di)
#pragma unroll
      for (int dj = 0; dj < 16; ++dj) p[di][dj] += q4[di] * k16[dj];
  }
  // qr (F_QR*aQR folded into qtr)
  const int baseq = i0 + rg * 4 - cg * 16 + 240;
  for (int c = 0; c < 32; ++c) {
    float q4[4];
    *(float4*)q4 = *(const float4*)&qtr[c * 64 + rg * 4];
    float rq[19];
    const float* rp = rel + (size_t)c * 511 + baseq;
#pragma unroll
    for (int u = 0; u < 19; ++u) rq[u] = rp[u];
#pragma unroll
    for (int di = 0; di < 4; ++di)
#pragma unroll
      for (int dj = 0; dj < 16; ++dj) p[di][dj] += q4[di] * rq[di - dj + 15];
  }
  __syncthreads();
  // stage ktr = bn(k) * (F_KR*aKR)
#pragma unroll
  for (int r = 0; r < 8; ++r) {
    int f = t + 256 * r;
    int row = f >> 6, c4 = f & 63;
    int o = g * 128 + 32 + row;
    float sc = qs[o], hh = qh[o];
    float4 v = *(const float4*)(qkv + ((size_t)b * OO + o) * NN + c4 * 4);
    *(float4*)&ktr[row * 256 + c4 * 4] = mul4(bn4(v, sc, hh), aKR);
  }
  __syncthreads();
  const int basek = cg * 16 - rg * 4 - i0 + 252;
  for (int c = 0; c < 32; ++c) {
    float k16[16];
#pragma unroll
    for (int q = 0; q < 4; ++q) *(float4*)&k16[q * 4] = *(const float4*)&ktr[c * 256 + cg * 16 + q * 4];
    float rk[19];
    const float* rp = rel + (size_t)(32 + c) * 511 + basek;
#pragma unroll
    for (int u = 0; u < 19; ++u) rk[u] = rp[u];
#pragma unroll
    for (int di = 0; di < 4; ++di)
#pragma unroll
      for (int dj = 0; dj < 16; ++dj) p[di][dj] += k16[dj] * rk[dj - di + 3];
  }

  // shift + softmax over j (row = 16 lanes sharing rg)
#pragma unroll
  for (int di = 0; di < 4; ++di) {
    float m = -1e30f;
#pragma unroll
    for (int dj = 0; dj < 16; ++dj) { p[di][dj] += SH; m = fmaxf(m, p[di][dj]); }
#pragma unroll
    for (int k = 1; k < 16; k <<= 1) m = fmaxf(m, __shfl_xor(m, k));
    float s = 0.f;
#pragma unroll
    for (int dj = 0; dj < 16; ++dj) { p[di][dj] = __expf(p[di][dj] - m); s += p[di][dj]; }
#pragma unroll
    for (int k = 1; k < 16; k <<= 1) s += __shfl_xor(s, k);
    float invs = 1.f / s;
#pragma unroll
    for (int dj = 0; dj < 16; ++dj) p[di][dj] *= invs;
  }
  __syncthreads();

  // phase B: sv and sve (sve scaled by F_SVE before storing, as in reference)
  for (int chunk = 0; chunk < 2; ++chunk) {
#pragma unroll
    for (int r = 0; r < 8; ++r) {
      int f = t + 256 * r;
      int row = f >> 6, c4 = f & 63;
      int o = g * 128 + 64 + chunk * 32 + row;
      float sc = qs[o], hh = qh[o];
      float4 v = *(const float4*)(qkv + ((size_t)b * OO + o) * NN + c4 * 4);
      *(float4*)&vt[row * 256 + c4 * 4] = bn4(v, sc, hh);
    }
    __syncthreads();
    for (int c = 0; c < 32; ++c) {
      float v16[16];
#pragma unroll
      for (int q = 0; q < 4; ++q) *(float4*)&v16[q * 4] = *(const float4*)&vt[c * 256 + cg * 16 + q * 4];
      float sp[4];
#pragma unroll
      for (int di = 0; di < 4; ++di) {
        float s = 0.f;
#pragma unroll
        for (int dj = 0; dj < 16; ++dj) s += p[di][dj] * v16[dj];
        sp[di] = s;
      }
#pragma unroll
      for (int di = 0; di < 4; ++di)
#pragma unroll
        for (int k = 1; k < 16; k <<= 1) sp[di] += __shfl_xor(sp[di], k);
      if (cg == 0) {
        float4 o4 = {sp[0], sp[1], sp[2], sp[3]};
        *(float4*)(svbuf + ((size_t)(b * 512 + g * 64 + chunk * 32 + c)) * NN + i0 + rg * 4) = o4;
      }
      float rv[19];
      const float* rp = rel + (size_t)(64 + chunk * 32 + c) * 511 + baseq;
#pragma unroll
      for (int u = 0; u < 19; ++u) rv[u] = rp[u];
      float se[4];
#pragma unroll
      for (int di = 0; di < 4; ++di) {
        float s = 0.f;
#pragma unroll
        for (int dj = 0; dj < 16; ++dj) s += p[di][dj] * rv[di - dj + 15];
        se[di] = s;
      }
#pragma unroll
      for (int di = 0; di < 4; ++di)
#pragma unroll
        for (int k = 1; k < 16; k <<= 1) se[di] += __shfl_xor(se[di], k);
      if (cg == 0) {
        float4 o4 = {se[0] * F_SVE, se[1] * F_SVE, se[2] * F_SVE, se[3] * F_SVE};
        *(float4*)(svebuf + ((size_t)(b * 512 + g * 64 + chunk * 32 + c)) * NN + i0 + rg * 4) = o4;
      }
    }
    __syncthreads();
  }
}

// ---------------- K6: final BN stats over sv / sve ----------------
__global__ __launch_bounds__(256) void k_out_stats(const float* __restrict__ svbuf,
                                                   const float* __restrict__ svebuf,
                                                   const float* __restrict__ go,
                                                   const float* __restrict__ bo,
                                                   float* __restrict__ osc,
                                                   float* __restrict__ osh) {
  const int bid = blockIdx.x;
  const int arr = bid >> 9, pch = bid & 511;
  const float* buf = arr ? svebuf : svbuf;
  const int t = threadIdx.x;
  float s = 0.f, ss = 0.f;
  for (int b = 0; b < BB; ++b) {
    float v = buf[((size_t)b * 512 + pch) * NN + t];
    s += v; ss += v * v;
  }
#pragma unroll
  for (int m = 1; m < 64; m <<= 1) { s += __shfl_xor(s, m); ss += __shfl_xor(ss, m); }
  __shared__ float rs[4], rss[4];
  int wv = t >> 6;
  if ((t & 63) == 0) { rs[wv] = s; rss[wv] = ss; }
  __syncthreads();
  if (t == 0) {
    s = rs[0] + rs[1] + rs[2] + rs[3];
    ss = rss[0] + rss[1] + rss[2] + rss[3];
    const float inv = 1.f / 16384.f;
    float m = s * inv;
    float var = ss * inv - m * m;
    float r = rsqrtf(var + 1e-5f);
    int o = pch * 2 + arr;
    float sc = go[o] * r;
    osc[bid] = sc;
    osh[bid] = bo[o] - m * sc;
  }
}

// ---------------- K7: combine ----------------
__global__ __launch_bounds__(256) void k_final(const float* __restrict__ svbuf,
                                               const float* __restrict__ svebuf,
                                               const float* __restrict__ osc,
                                               const float* __restrict__ osh,
                                               float* __restrict__ out) {
  const size_t f = (size_t)blockIdx.x * 256 + threadIdx.x;  // float4 index
  const int pch = (int)((f >> 6) & 511);
  float4 a = ((const float4*)svbuf)[f];
  float4 e = ((const float4*)svebuf)[f];
  float s1 = osc[pch], h1 = osh[pch];
  float s2 = osc[512 + pch], h2 = osh[512 + pch];
  float hh = h1 + h2;
  float4 o;
  o.x = a.x * s1 + e.x * s2 + hh;
  o.y = a.y * s1 + e.y * s2 + hh;
  o.z = a.z * s1 + e.z * s2 + hh;
  o.w = a.w * s1 + e.w * s2 + hh;
  ((float4*)out)[f] = o;
}

extern "C" void kernel_launch(void* const* d_in, const int* in_sizes, int n_in,
                              void* d_out, int out_size, void* d_ws, size_t ws_size,
                              hipStream_t stream) {
  const float* x     = (const float*)d_in[0];
  const float* w     = (const float*)d_in[1];
  const float* rel   = (const float*)d_in[2];
  const float* g_qkv = (const float*)d_in[3];
  const float* b_qkv = (const float*)d_in[4];
  const float* g_sim = (const float*)d_in[5];
  const float* b_sim = (const float*)d_in[6];
  const float* g_out = (const float*)d_in[7];
  const float* b_out = (const float*)d_in[8];

  float* ws = (float*)d_ws;
  float* qkv      = ws;                       // 16,777,216
  float* sv       = qkv + 16777216;           // 8,388,608
  float* sve      = sv + 8388608;             // 8,388,608
  float* qs       = sve + 8388608;            // 1024
  float* qh       = qs + 1024;                // 1024
  float* simacc   = qh + 1024;                // 48
  float* simscale = simacc + 48;              // 24
  float* simshift = simscale + 24;            // 8
  float* osc      = simshift + 8;             // 1024
  float* osh      = osc + 1024;               // 1024
  // total ~128 MiB of d_ws

  hipMemsetAsync(simacc, 0, 48 * sizeof(float), stream);

  k_qkv_gemm<<<dim3(2, 8, 64), 256, 0, stream>>>(x, w, qkv);
  k_qkv_stats<<<1024, 256, 0, stream>>>(qkv, g_qkv, b_qkv, qs, qh);
  k_pass1<<<dim3(4, 512), 256, 0, stream>>>(qkv, rel, qs, qh, simacc);
  k_sim_finalize<<<1, 32, 0, stream>>>(simacc, g_sim, b_sim, simscale, simshift);
  k_pass2<<<dim3(4, 512), 256, 0, stream>>>(qkv, rel, qs, qh, simscale, simshift, sv, sve);
  k_out_stats<<<1024, 256, 0, stream>>>(sv, sve, g_out, b_out, osc, osh);
  k_final<<<8192, 256, 0, stream>>>(sv, sve, osc, osh, (float*)d_out);
}

// Round 3
// 860.769 us; speedup vs baseline: 1.1518x; 1.1518x over previous
//
#include <hip/hip_runtime.h>

#define NN 256
#define CC 512
#define OO 1024
#define BB 64

#define F_QR 0.1f
#define F_KR 0.1f
#define F_SVE 0.1f

__device__ inline float4 bn4(float4 v, float sc, float hh) {
  return make_float4(v.x * sc + hh, v.y * sc + hh, v.z * sc + hh, v.w * sc + hh);
}

// ---------------- K0: pad rel rows 511 -> 512 (enables aligned float4 rel loads)
__global__ void k_relpad(const float* __restrict__ rel, float* __restrict__ relp) {
  const int row = blockIdx.x;
  const int t = threadIdx.x;
  for (int u = t; u < 511; u += 256) relp[row * 512 + u] = rel[row * 511 + u];
  if (t == 0) relp[row * 512 + 511] = 0.f;
}

// ---------------- K1: qkv[b][o][n] = sum_c W[o][c] * x[b][n][c] ----------------
__global__ __launch_bounds__(256) void k_qkv_gemm(const float* __restrict__ x,
                                                  const float* __restrict__ w,
                                                  float* __restrict__ qkv) {
  const int b = blockIdx.z, ot = blockIdx.y, nt = blockIdx.x;
  const int o0 = ot * 128, n0 = nt * 128;
  __shared__ float As[32][132];
  __shared__ float Bs[32][132];
  const int t = threadIdx.x;
  const int to = t >> 4, tn = t & 15;
  float acc[8][8];
#pragma unroll
  for (int i = 0; i < 8; ++i)
#pragma unroll
    for (int j = 0; j < 8; ++j) acc[i][j] = 0.f;

  const float* wbase = w + (size_t)o0 * CC;
  const float* xbase = x + (size_t)b * NN * CC + (size_t)n0 * CC;

  for (int c0 = 0; c0 < CC; c0 += 32) {
#pragma unroll
    for (int r = 0; r < 4; ++r) {
      int f = t + 256 * r;
      int row = f >> 3, cq = f & 7;
      float4 w4 = *(const float4*)(wbase + (size_t)row * CC + c0 + cq * 4);
      As[cq * 4 + 0][row] = w4.x; As[cq * 4 + 1][row] = w4.y;
      As[cq * 4 + 2][row] = w4.z; As[cq * 4 + 3][row] = w4.w;
      float4 x4 = *(const float4*)(xbase + (size_t)row * CC + c0 + cq * 4);
      Bs[cq * 4 + 0][row] = x4.x; Bs[cq * 4 + 1][row] = x4.y;
      Bs[cq * 4 + 2][row] = x4.z; Bs[cq * 4 + 3][row] = x4.w;
    }
    __syncthreads();
#pragma unroll
    for (int kk = 0; kk < 32; ++kk) {
      float a[8], bb[8];
      *(float4*)&a[0] = *(const float4*)&As[kk][to * 8];
      *(float4*)&a[4] = *(const float4*)&As[kk][to * 8 + 4];
      *(float4*)&bb[0] = *(const float4*)&Bs[kk][tn * 8];
      *(float4*)&bb[4] = *(const float4*)&Bs[kk][tn * 8 + 4];
#pragma unroll
      for (int i = 0; i < 8; ++i)
#pragma unroll
        for (int j = 0; j < 8; ++j) acc[i][j] += a[i] * bb[j];
    }
    __syncthreads();
  }
#pragma unroll
  for (int i = 0; i < 8; ++i) {
    float* dst = qkv + ((size_t)b * OO + o0 + to * 8 + i) * NN + n0 + tn * 8;
    float4 v0 = {acc[i][0], acc[i][1], acc[i][2], acc[i][3]};
    float4 v1 = {acc[i][4], acc[i][5], acc[i][6], acc[i][7]};
    *(float4*)dst = v0;
    *(float4*)(dst + 4) = v1;
  }
}

// ---------------- K2: per-channel BN scale/shift for qkv ----------------
__global__ __launch_bounds__(256) void k_qkv_stats(const float* __restrict__ qkv,
                                                   const float* __restrict__ gq,
                                                   const float* __restrict__ bq,
                                                   float* __restrict__ qs,
                                                   float* __restrict__ qh) {
  const int o = blockIdx.x;
  const int t = threadIdx.x;
  float s = 0.f, ss = 0.f;
  for (int b = 0; b < BB; ++b) {
    float v = qkv[((size_t)b * OO + o) * NN + t];
    s += v; ss += v * v;
  }
#pragma unroll
  for (int m = 1; m < 64; m <<= 1) { s += __shfl_xor(s, m); ss += __shfl_xor(ss, m); }
  __shared__ float rs[4], rss[4];
  int wv = t >> 6;
  if ((t & 63) == 0) { rs[wv] = s; rss[wv] = ss; }
  __syncthreads();
  if (t == 0) {
    s = rs[0] + rs[1] + rs[2] + rs[3];
    ss = rss[0] + rss[1] + rss[2] + rss[3];
    const float inv = 1.f / (float)(BB * NN);
    float m = s * inv;
    float var = ss * inv - m * m;
    float r = rsqrtf(var + 1e-5f);
    float sc = gq[o] * r;
    qs[o] = sc;
    qh[o] = bq[o] - m * sc;
  }
}

// ---------------- pass1: stats of qk/qr/kr ----------------
__device__ inline void reduce_term3(const float (&acc)[4][4][4], int term, float F, float* s_sh) {
  float s = 0.f, ss = 0.f;
#pragma unroll
  for (int di = 0; di < 4; ++di)
#pragma unroll
    for (int q = 0; q < 4; ++q)
#pragma unroll
      for (int dj = 0; dj < 4; ++dj) { float v = acc[di][q][dj]; s += v; ss += v * v; }
  s *= F;
  ss *= F * F;
#pragma unroll
  for (int m = 1; m < 64; m <<= 1) { s += __shfl_xor(s, m); ss += __shfl_xor(ss, m); }
  if ((threadIdx.x & 63) == 0) {
    atomicAdd(&s_sh[term * 2 + 0], s);
    atomicAdd(&s_sh[term * 2 + 1], ss);
  }
}

__global__ __launch_bounds__(256) void k_pass1(const float* __restrict__ qkv,
                                               const float* __restrict__ relp,
                                               const float* __restrict__ qs,
                                               const float* __restrict__ qh,
                                               float* __restrict__ simacc) {
  __shared__ float qt[2048];
  __shared__ float kt[8192];
  __shared__ float s_sh[6];
  const int it = blockIdx.x, bg = blockIdx.y;
  const int b = bg >> 3, g = bg & 7, i0 = it * 64;
  const int t = threadIdx.x, rg = t >> 4, cg = t & 15;
  if (t < 6) s_sh[t] = 0.f;

#pragma unroll
  for (int r = 0; r < 2; ++r) {
    int f = t + 256 * r;
    int row = f >> 4, c4 = f & 15;
    int o = g * 128 + row;
    float sc = qs[o], hh = qh[o];
    float4 v = *(const float4*)(qkv + ((size_t)b * OO + o) * NN + i0 + c4 * 4);
    *(float4*)&qt[row * 64 + c4 * 4] = bn4(v, sc, hh);
  }
#pragma unroll
  for (int r = 0; r < 8; ++r) {
    int f = t + 256 * r;
    int row = f >> 6, c4 = f & 63;
    int o = g * 128 + 32 + row;
    float sc = qs[o], hh = qh[o];
    float4 v = *(const float4*)(qkv + ((size_t)b * OO + o) * NN + c4 * 4);
    *(float4*)&kt[row * 256 + c4 * 4] = bn4(v, sc, hh);
  }
  __syncthreads();

  float acc[4][4][4];
  // ---- qk ----
#pragma unroll
  for (int di = 0; di < 4; ++di)
#pragma unroll
    for (int q = 0; q < 4; ++q)
#pragma unroll
      for (int dj = 0; dj < 4; ++dj) acc[di][q][dj] = 0.f;
  for (int c = 0; c < 32; ++c) {
    float q4[4];
    *(float4*)q4 = *(const float4*)&qt[c * 64 + rg * 4];
    float k16[4][4];
#pragma unroll
    for (int q = 0; q < 4; ++q) *(float4*)k16[q] = *(const float4*)&kt[c * 256 + q * 64 + cg * 4];
#pragma unroll
    for (int di = 0; di < 4; ++di)
#pragma unroll
      for (int q = 0; q < 4; ++q)
#pragma unroll
        for (int dj = 0; dj < 4; ++dj) acc[di][q][dj] += q4[di] * k16[q][dj];
  }
  reduce_term3(acc, 0, 1.0f, s_sh);

  // ---- qr ----
#pragma unroll
  for (int di = 0; di < 4; ++di)
#pragma unroll
    for (int q = 0; q < 4; ++q)
#pragma unroll
      for (int dj = 0; dj < 4; ++dj) acc[di][q][dj] = 0.f;
  for (int c = 0; c < 32; ++c) {
    float q4[4];
    *(float4*)q4 = *(const float4*)&qt[c * 64 + rg * 4];
#pragma unroll
    for (int q = 0; q < 4; ++q) {
      const float* rp = relp + c * 512 + (i0 + rg * 4 - cg * 4 - 64 * q + 252);
      float rq[8];
      *(float4*)&rq[0] = *(const float4*)rp;
      *(float4*)&rq[4] = *(const float4*)(rp + 4);
#pragma unroll
      for (int di = 0; di < 4; ++di)
#pragma unroll
        for (int dj = 0; dj < 4; ++dj) acc[di][q][dj] += q4[di] * rq[di - dj + 3];
    }
  }
  reduce_term3(acc, 1, F_QR, s_sh);

  // ---- kr ----
#pragma unroll
  for (int di = 0; di < 4; ++di)
#pragma unroll
    for (int q = 0; q < 4; ++q)
#pragma unroll
      for (int dj = 0; dj < 4; ++dj) acc[di][q][dj] = 0.f;
  for (int c = 0; c < 32; ++c) {
    float k16[4][4];
#pragma unroll
    for (int q = 0; q < 4; ++q) *(float4*)k16[q] = *(const float4*)&kt[c * 256 + q * 64 + cg * 4];
#pragma unroll
    for (int q = 0; q < 4; ++q) {
      const float* rp = relp + (32 + c) * 512 + (64 * q + cg * 4 - i0 - rg * 4 + 252);
      float rk[8];
      *(float4*)&rk[0] = *(const float4*)rp;
      *(float4*)&rk[4] = *(const float4*)(rp + 4);
#pragma unroll
      for (int di = 0; di < 4; ++di)
#pragma unroll
        for (int dj = 0; dj < 4; ++dj) acc[di][q][dj] += k16[q][dj] * rk[dj - di + 3];
    }
  }
  reduce_term3(acc, 2, F_KR, s_sh);

  __syncthreads();
  if (t < 6) {
    int term = t >> 1, isq = t & 1;
    atomicAdd(&simacc[isq * 24 + term * 8 + g], s_sh[t]);
  }
}

// ---------------- finalize sim BN coefficients ----------------
__global__ void k_sim_finalize(const float* __restrict__ simacc,
                               const float* __restrict__ gs,
                               const float* __restrict__ bs,
                               float* __restrict__ simscale,
                               float* __restrict__ simshift) {
  const int t = threadIdx.x;
  __shared__ float sh[24];
  if (t < 24) {
    const float inv = 1.f / (64.f * 256.f * 256.f);
    float m = simacc[t] * inv;
    float var = simacc[24 + t] * inv - m * m;
    float a = gs[t] * rsqrtf(var + 1e-5f);
    simscale[t] = a;
    sh[t] = bs[t] - m * a;
  }
  __syncthreads();
  if (t < 8) simshift[t] = sh[t] + sh[8 + t] + sh[16 + t];
}

// ---------------- pass2: sim + softmax + sv/sve ----------------
__global__ __launch_bounds__(256) void k_pass2(const float* __restrict__ qkv,
                                               const float* __restrict__ relp,
                                               const float* __restrict__ qs,
                                               const float* __restrict__ qh,
                                               const float* __restrict__ simscale,
                                               const float* __restrict__ simshift,
                                               float* __restrict__ svbuf,
                                               float* __restrict__ svebuf) {
  __shared__ float qt[2048];
  __shared__ float kt[8192];  // reused as vt in phase B

  const int it = blockIdx.x, bg = blockIdx.y;
  const int b = bg >> 3, g = bg & 7, i0 = it * 64;
  const int t = threadIdx.x, rg = t >> 4, cg = t & 15;
  const float aQK = simscale[g];
  const float aQR = F_QR * simscale[8 + g];
  const float aKR = F_KR * simscale[16 + g];
  const float SH = simshift[g];

#pragma unroll
  for (int r = 0; r < 2; ++r) {
    int f = t + 256 * r;
    int row = f >> 4, c4 = f & 15;
    int o = g * 128 + row;
    float sc = qs[o], hh = qh[o];
    float4 v = *(const float4*)(qkv + ((size_t)b * OO + o) * NN + i0 + c4 * 4);
    *(float4*)&qt[row * 64 + c4 * 4] = bn4(v, sc, hh);
  }
#pragma unroll
  for (int r = 0; r < 8; ++r) {
    int f = t + 256 * r;
    int row = f >> 6, c4 = f & 63;
    int o = g * 128 + 32 + row;
    float sc = qs[o], hh = qh[o];
    float4 v = *(const float4*)(qkv + ((size_t)b * OO + o) * NN + c4 * 4);
    *(float4*)&kt[row * 256 + c4 * 4] = bn4(v, sc, hh);
  }
  __syncthreads();

  float p[4][4][4];
#pragma unroll
  for (int di = 0; di < 4; ++di)
#pragma unroll
    for (int q = 0; q < 4; ++q)
#pragma unroll
      for (int dj = 0; dj < 4; ++dj) p[di][q][dj] = 0.f;

  // unified logits loop: qk + qr + kr share the q4/k16 LDS loads
  for (int c = 0; c < 32; ++c) {
    float q4[4];
    *(float4*)q4 = *(const float4*)&qt[c * 64 + rg * 4];
    float k16[4][4];
#pragma unroll
    for (int q = 0; q < 4; ++q) *(float4*)k16[q] = *(const float4*)&kt[c * 256 + q * 64 + cg * 4];
    float q4a[4], q4r[4];
#pragma unroll
    for (int di = 0; di < 4; ++di) { q4a[di] = q4[di] * aQK; q4r[di] = q4[di] * aQR; }
    // qk
#pragma unroll
    for (int di = 0; di < 4; ++di)
#pragma unroll
      for (int q = 0; q < 4; ++q)
#pragma unroll
        for (int dj = 0; dj < 4; ++dj) p[di][q][dj] += q4a[di] * k16[q][dj];
    // qr
#pragma unroll
    for (int q = 0; q < 4; ++q) {
      const float* rp = relp + c * 512 + (i0 + rg * 4 - cg * 4 - 64 * q + 252);
      float rq[8];
      *(float4*)&rq[0] = *(const float4*)rp;
      *(float4*)&rq[4] = *(const float4*)(rp + 4);
#pragma unroll
      for (int di = 0; di < 4; ++di)
#pragma unroll
        for (int dj = 0; dj < 4; ++dj) p[di][q][dj] += q4r[di] * rq[di - dj + 3];
    }
    // kr (fold aKR into k16, which is dead after this)
#pragma unroll
    for (int q = 0; q < 4; ++q)
#pragma unroll
      for (int dj = 0; dj < 4; ++dj) k16[q][dj] *= aKR;
#pragma unroll
    for (int q = 0; q < 4; ++q) {
      const float* rp = relp + (32 + c) * 512 + (64 * q + cg * 4 - i0 - rg * 4 + 252);
      float rk[8];
      *(float4*)&rk[0] = *(const float4*)rp;
      *(float4*)&rk[4] = *(const float4*)(rp + 4);
#pragma unroll
      for (int di = 0; di < 4; ++di)
#pragma unroll
        for (int dj = 0; dj < 4; ++dj) p[di][q][dj] += k16[q][dj] * rk[dj - di + 3];
    }
  }

  // shift + softmax over j (16 cg lanes per row i)
#pragma unroll
  for (int di = 0; di < 4; ++di) {
    float m = -1e30f;
#pragma unroll
    for (int q = 0; q < 4; ++q)
#pragma unroll
      for (int dj = 0; dj < 4; ++dj) { p[di][q][dj] += SH; m = fmaxf(m, p[di][q][dj]); }
#pragma unroll
    for (int k = 1; k < 16; k <<= 1) m = fmaxf(m, __shfl_xor(m, k));
    float s = 0.f;
#pragma unroll
    for (int q = 0; q < 4; ++q)
#pragma unroll
      for (int dj = 0; dj < 4; ++dj) { p[di][q][dj] = __expf(p[di][q][dj] - m); s += p[di][q][dj]; }
#pragma unroll
    for (int k = 1; k < 16; k <<= 1) s += __shfl_xor(s, k);
    float invs = 1.f / s;
#pragma unroll
    for (int q = 0; q < 4; ++q)
#pragma unroll
      for (int dj = 0; dj < 4; ++dj) p[di][q][dj] *= invs;
  }
  __syncthreads();

  // phase B: sv and sve
  for (int chunk = 0; chunk < 2; ++chunk) {
#pragma unroll
    for (int r = 0; r < 8; ++r) {
      int f = t + 256 * r;
      int row = f >> 6, c4 = f & 63;
      int o = g * 128 + 64 + chunk * 32 + row;
      float sc = qs[o], hh = qh[o];
      float4 v = *(const float4*)(qkv + ((size_t)b * OO + o) * NN + c4 * 4);
      *(float4*)&kt[row * 256 + c4 * 4] = bn4(v, sc, hh);
    }
    __syncthreads();
    for (int c = 0; c < 32; ++c) {
      float v16[4][4];
#pragma unroll
      for (int q = 0; q < 4; ++q) *(float4*)v16[q] = *(const float4*)&kt[c * 256 + q * 64 + cg * 4];
      float sp[4], se[4];
#pragma unroll
      for (int di = 0; di < 4; ++di) {
        float s = 0.f;
#pragma unroll
        for (int q = 0; q < 4; ++q)
#pragma unroll
          for (int dj = 0; dj < 4; ++dj) s += p[di][q][dj] * v16[q][dj];
        sp[di] = s;
      }
      float rv[4][8];
#pragma unroll
      for (int q = 0; q < 4; ++q) {
        const float* rp = relp + (64 + chunk * 32 + c) * 512 + (i0 + rg * 4 - cg * 4 - 64 * q + 252);
        *(float4*)&rv[q][0] = *(const float4*)rp;
        *(float4*)&rv[q][4] = *(const float4*)(rp + 4);
      }
#pragma unroll
      for (int di = 0; di < 4; ++di) {
        float s = 0.f;
#pragma unroll
        for (int q = 0; q < 4; ++q)
#pragma unroll
          for (int dj = 0; dj < 4; ++dj) s += p[di][q][dj] * rv[q][di - dj + 3];
        se[di] = s;
      }
#pragma unroll
      for (int di = 0; di < 4; ++di)
#pragma unroll
        for (int k = 1; k < 16; k <<= 1) {
          sp[di] += __shfl_xor(sp[di], k);
          se[di] += __shfl_xor(se[di], k);
        }
      if (cg == 0) {
        float4 o1 = {sp[0], sp[1], sp[2], sp[3]};
        *(float4*)(svbuf + ((size_t)(b * 512 + g * 64 + chunk * 32 + c)) * NN + i0 + rg * 4) = o1;
        float4 o2 = {se[0] * F_SVE, se[1] * F_SVE, se[2] * F_SVE, se[3] * F_SVE};
        *(float4*)(svebuf + ((size_t)(b * 512 + g * 64 + chunk * 32 + c)) * NN + i0 + rg * 4) = o2;
      }
    }
    __syncthreads();
  }
}

// ---------------- K6: final BN stats over sv / sve ----------------
__global__ __launch_bounds__(256) void k_out_stats(const float* __restrict__ svbuf,
                                                   const float* __restrict__ svebuf,
                                                   const float* __restrict__ go,
                                                   const float* __restrict__ bo,
                                                   float* __restrict__ osc,
                                                   float* __restrict__ osh) {
  const int bid = blockIdx.x;
  const int arr = bid >> 9, pch = bid & 511;
  const float* buf = arr ? svebuf : svbuf;
  const int t = threadIdx.x;
  float s = 0.f, ss = 0.f;
  for (int b = 0; b < BB; ++b) {
    float v = buf[((size_t)b * 512 + pch) * NN + t];
    s += v; ss += v * v;
  }
#pragma unroll
  for (int m = 1; m < 64; m <<= 1) { s += __shfl_xor(s, m); ss += __shfl_xor(ss, m); }
  __shared__ float rs[4], rss[4];
  int wv = t >> 6;
  if ((t & 63) == 0) { rs[wv] = s; rss[wv] = ss; }
  __syncthreads();
  if (t == 0) {
    s = rs[0] + rs[1] + rs[2] + rs[3];
    ss = rss[0] + rss[1] + rss[2] + rss[3];
    const float inv = 1.f / 16384.f;
    float m = s * inv;
    float var = ss * inv - m * m;
    float r = rsqrtf(var + 1e-5f);
    int o = pch * 2 + arr;
    float sc = go[o] * r;
    osc[bid] = sc;
    osh[bid] = bo[o] - m * sc;
  }
}

// ---------------- K7: combine ----------------
__global__ __launch_bounds__(256) void k_final(const float* __restrict__ svbuf,
                                               const float* __restrict__ svebuf,
                                               const float* __restrict__ osc,
                                               const float* __restrict__ osh,
                                               float* __restrict__ out) {
  const size_t f = (size_t)blockIdx.x * 256 + threadIdx.x;  // float4 index
  const int pch = (int)((f >> 6) & 511);
  float4 a = ((const float4*)svbuf)[f];
  float4 e = ((const float4*)svebuf)[f];
  float s1 = osc[pch], h1 = osh[pch];
  float s2 = osc[512 + pch], h2 = osh[512 + pch];
  float hh = h1 + h2;
  float4 o;
  o.x = a.x * s1 + e.x * s2 + hh;
  o.y = a.y * s1 + e.y * s2 + hh;
  o.z = a.z * s1 + e.z * s2 + hh;
  o.w = a.w * s1 + e.w * s2 + hh;
  ((float4*)out)[f] = o;
}

extern "C" void kernel_launch(void* const* d_in, const int* in_sizes, int n_in,
                              void* d_out, int out_size, void* d_ws, size_t ws_size,
                              hipStream_t stream) {
  const float* x     = (const float*)d_in[0];
  const float* w     = (const float*)d_in[1];
  const float* rel   = (const float*)d_in[2];
  const float* g_qkv = (const float*)d_in[3];
  const float* b_qkv = (const float*)d_in[4];
  const float* g_sim = (const float*)d_in[5];
  const float* b_sim = (const float*)d_in[6];
  const float* g_out = (const float*)d_in[7];
  const float* b_out = (const float*)d_in[8];

  float* ws = (float*)d_ws;
  float* qkv      = ws;                       // 16,777,216
  float* sv       = qkv + 16777216;           // 8,388,608
  float* sve      = sv + 8388608;             // 8,388,608
  float* qs       = sve + 8388608;            // 1024
  float* qh       = qs + 1024;                // 1024
  float* simacc   = qh + 1024;                // 48
  float* simscale = simacc + 48;              // 24
  float* simshift = simscale + 24;            // 8
  float* osc      = simshift + 8;             // 1024
  float* osh      = osc + 1024;               // 1024

  // relp (128x512 padded rel copy) lives in d_out's tail: d_out is dead until
  // k_final fully overwrites it, and relp is last read in k_pass2.
  float* relp = (float*)d_out;                // 65536 floats of 8.39M

  hipMemsetAsync(simacc, 0, 48 * sizeof(float), stream);

  k_relpad<<<128, 256, 0, stream>>>(rel, relp);
  k_qkv_gemm<<<dim3(2, 8, 64), 256, 0, stream>>>(x, w, qkv);
  k_qkv_stats<<<1024, 256, 0, stream>>>(qkv, g_qkv, b_qkv, qs, qh);
  k_pass1<<<dim3(4, 512), 256, 0, stream>>>(qkv, relp, qs, qh, simacc);
  k_sim_finalize<<<1, 32, 0, stream>>>(simacc, g_sim, b_sim, simscale, simshift);
  k_pass2<<<dim3(4, 512), 256, 0, stream>>>(qkv, relp, qs, qh, simscale, simshift, sv, sve);
  k_out_stats<<<1024, 256, 0, stream>>>(sv, sve, g_out, b_out, osc, osh);
  k_final<<<8192, 256, 0, stream>>>(sv, sve, osc, osh, (float*)d_out);
}